// Round 6
// baseline (238.408 us; speedup 1.0000x reference)
//
#include <hip/hip_runtime.h>

#define BB 256
#define SS 200
#define MM 32
#define KDIM 128
#define VDIM 256
#define QDIM 128
#define HH 64
#define NROWS 10001
#define NSAMP (BB*SS)
#define INDIM (VDIM+QDIM)
#define DHS 8192
#define DHMASK (DHS-1)
#define XR 16
#define NB_ATTN 2501

typedef unsigned long long u64;
typedef unsigned int u32;
typedef float f16v __attribute__((ext_vector_type(16)));

__device__ __forceinline__ float fexp(float x){ return __builtin_amdgcn_exp2f(x * 1.44269504f); }
__device__ __forceinline__ float fsigm(float x){ return __builtin_amdgcn_rcpf(1.f + fexp(-x)); }
__device__ __forceinline__ float ftanh(float x){ return 1.f - 2.f*__builtin_amdgcn_rcpf(1.f + fexp(2.f*x)); }
__device__ __forceinline__ int clampq(int q){ return q < 0 ? 0 : (q > NROWS-1 ? NROWS-1 : q); }

__device__ __forceinline__ u32 hash64(u64 x){
  x ^= x >> 33; x *= 0xff51afd7ed558ccdULL;
  x ^= x >> 33; x *= 0xc4ceb9fe1a85ec53ULL;
  x ^= x >> 33;
  return (u32)x;
}

__device__ __forceinline__ u64 shflx64(u64 v, int m){
  int lo = __shfl_xor((int)(u32)v, m, 64);
  int hi = __shfl_xor((int)(u32)(v >> 32), m, 64);
  return ((u64)(u32)hi << 32) | (u32)lo;
}

// transposes + present init:
// WQT4[(d4*256+j)*4+dd]=W_ih[j][VDIM+4d4+dd]; KT[d*32+m]=key_mem[m][d];
// WVT[v*256+j]=W_ih[j][v]; present[:]=0
__global__ void k_tr(const float* __restrict__ W_ih, const float* __restrict__ key_mem,
                     float* __restrict__ WQT4, float* __restrict__ KT,
                     float* __restrict__ WVT, u32* __restrict__ present){
  int idx = blockIdx.x*256 + threadIdx.x;
  if (idx < 131072) {
    int dd = idx & 3, j = (idx >> 2) & 255, d4 = idx >> 10;
    WQT4[idx] = W_ih[j*INDIM + VDIM + 4*d4 + dd];
  } else if (idx < 135168) {
    int t = idx - 131072;
    int m = t & 31, d = t >> 5; KT[t] = key_mem[m*KDIM + d];
  } else if (idx < 200704) {
    int t = idx - 135168;
    int j = t & 255, v = t >> 8; WVT[v*256 + j] = W_ih[j*INDIM + v];
  } else {
    int t = idx - 200704;
    if (t < NROWS) present[t] = 0u;
  }
}

// fused front: blocks [0,2501) attn ; [2501,2533) vw ; [2533,2733) mark
__global__ __launch_bounds__(256) void k_front(
    const float* __restrict__ emb, const float* __restrict__ KT,
    const float* __restrict__ val, const float* __restrict__ WVT,
    const int* __restrict__ q_data,
    float* __restrict__ CW, u64* __restrict__ KEYT,
    float* __restrict__ VW, u32* __restrict__ present){
  int bid = blockIdx.x;
  if (bid < NB_ATTN) {
    // ---- attn: one wave per row ----
    int w = threadIdx.x >> 6, l = threadIdx.x & 63;
    int n = bid*4 + w;
    __shared__ float se[4][QDIM];
    bool valid = (n < NROWS);
    if (valid) {
      se[w][l]      = emb[n*QDIM + l];
      se[w][l + 64] = emb[n*QDIM + l + 64];
    }
    __syncthreads();
    int m = l & 31;
    float logit = 0.f;
    if (valid && l < 32)
      for (int d = 0; d < KDIM; ++d) logit += se[w][d] * KT[d*32 + m];
    float mx = logit;
    #pragma unroll
    for (int msk = 16; msk >= 1; msk >>= 1) mx = fmaxf(mx, __shfl_xor(mx, msk, 64));
    float e = (l < 32) ? expf(logit - mx) : 0.f;    // precise expf: trit boundaries
    float sum = e;
    #pragma unroll
    for (int msk = 16; msk >= 1; msk >>= 1) sum += __shfl_xor(sum, msk, 64);
    float cw = e / sum;
    float wv = fminf((cw - 0.075f)/0.013f, (1.0f - cw)/0.912f);
    wv = fmaxf(wv, 0.f);
    int iv = (wv >= 0.6f) ? 2 : ((wv >= 0.1f) ? 1 : 0);
    int ee = (m < 16) ? m + 16 : m - 16;   // key = kh*3^16 + kl (reference packing)
    u64 p3 = 1;
    for (int i = 0; i < 31; ++i) if (i < ee) p3 *= 3ULL;
    u64 term = (valid && l < 32) ? (u64)iv * p3 : 0ULL;
    #pragma unroll
    for (int msk = 16; msk >= 1; msk >>= 1) term += shflx64(term, msk);
    if (valid && l < 32) CW[n*256 + m] = cw;
    if (valid && l == 0) KEYT[n] = term;
  } else if (bid < NB_ATTN + MM) {
    // ---- vw: VW[m][j] = sum_v val[m][v]*WVT[v][j] ----
    int m = bid - NB_ATTN, j = threadIdx.x;
    __shared__ float sval[VDIM];
    sval[j] = val[m*VDIM + j];
    __syncthreads();
    float a0=0.f, a1=0.f, a2=0.f, a3=0.f;
    for (int v = 0; v < VDIM; v += 4) {
      a0 += sval[v+0]*WVT[(v+0)*256 + j];
      a1 += sval[v+1]*WVT[(v+1)*256 + j];
      a2 += sval[v+2]*WVT[(v+2)*256 + j];
      a3 += sval[v+3]*WVT[(v+3)*256 + j];
    }
    VW[m*256 + j] = (a0+a1)+(a2+a3);
  } else {
    // ---- mark ----
    int i = (bid - NB_ATTN - MM)*256 + threadIdx.x;
    if (i < NSAMP) present[clampq(q_data[i])] = 1u;
  }
}

// XW4 row = bias + cw.VW + emb.WqT: 16 rows/block tiled GEMM
__global__ __launch_bounds__(256) void k_xw(
    const float* __restrict__ CW, const float* __restrict__ emb,
    const float* __restrict__ VW, const float* __restrict__ WQT4,
    const float* __restrict__ b_ih, const float* __restrict__ b_hh,
    float* __restrict__ XW4){
  int base = blockIdx.x * XR;
  int j = threadIdx.x;
  __shared__ float scw[XR][32];
  __shared__ __align__(16) float ses[XR][QDIM];
  for (int idx = j; idx < XR*32; idx += 256) {
    int r = idx >> 5, m = idx & 31, n = base + r;
    scw[r][m] = (n < NROWS) ? CW[n*256 + m] : 0.f;
  }
  for (int idx = j; idx < XR*QDIM; idx += 256) {
    int r = idx >> 7, d = idx & 127, n = base + r;
    ses[r][d] = (n < NROWS) ? emb[n*QDIM + d] : 0.f;
  }
  __syncthreads();
  float bias = b_ih[j] + b_hh[j];
  float acc[XR];
  #pragma unroll
  for (int r = 0; r < XR; ++r) acc[r] = bias;
  for (int m = 0; m < MM; ++m) {
    float wv = VW[m*256 + j];
    #pragma unroll
    for (int r = 0; r < XR; ++r) acc[r] += scw[r][m] * wv;
  }
  for (int d4 = 0; d4 < QDIM/4; ++d4) {
    float4 wq = *(const float4*)(WQT4 + d4*1024 + j*4);
    #pragma unroll
    for (int r = 0; r < XR; ++r) {
      float4 ev = *(const float4*)(&ses[r][4*d4]);
      acc[r] += ev.x*wq.x + ev.y*wq.y + ev.z*wq.z + ev.w*wq.w;
    }
  }
  int gate = j >> 6, unit = j & 63;
  #pragma unroll
  for (int r = 0; r < XR; ++r)
    if (base + r < NROWS) XW4[(size_t)(base + r)*256 + 4*unit + gate] = acc[r];
}

__global__ __launch_bounds__(1024) void k_dedup(
    const u32* __restrict__ present, const u64* __restrict__ KEYT,
    u32* __restrict__ g_htab, u32* __restrict__ g_pay,
    u32* __restrict__ counter, u64* __restrict__ uniq){
  __shared__ u32 sh_tab[DHS];
  __shared__ u32 sh_pay[DHS];
  __shared__ u32 sh_cnt;
  int tid = threadIdx.x;
  for (int i = tid; i < DHS; i += 1024) sh_tab[i] = 0u;
  if (tid == 0) sh_cnt = 0u;
  __syncthreads();
  for (int n = tid; n < NROWS; n += 1024) {
    if (present[n] != 1u) continue;
    u64 key = KEYT[n];
    u32 h = hash64(key) & DHMASK;
    while (true) {
      u32 cur = sh_tab[h];
      if (cur != 0u) {
        if (KEYT[cur-1u] == key) break;
        h = (h + 1) & DHMASK; continue;
      }
      u32 prev = atomicCAS(&sh_tab[h], 0u, (u32)(n + 1));
      if (prev == 0u) {
        u32 idx = atomicAdd(&sh_cnt, 1u);
        uniq[idx] = key;
        sh_pay[h] = idx;
        break;
      }
      if (KEYT[prev-1u] == key) break;
      h = (h + 1) & DHMASK;
    }
  }
  __syncthreads();
  for (int i = tid; i < DHS; i += 1024) {
    u32 v = sh_tab[i];
    g_htab[i] = v;
    g_pay[i]  = v ? sh_pay[i] : 0u;
  }
  if (tid == 0) *counter = sh_cnt;
}

__global__ __launch_bounds__(256) void k_rank(const u64* __restrict__ uniq,
                                              const u32* __restrict__ counter,
                                              u32* __restrict__ RANK){
  __shared__ u64 chunk[2048];
  u32 U = *counter;
  int u = blockIdx.x*256 + threadIdx.x;
  u64 mykey = (u < (int)U) ? uniq[u] : 0;
  u32 cnt = 0;
  for (u32 base = 0; base < U; base += 2048) {
    u32 n = (U - base < 2048u) ? (U - base) : 2048u;
    __syncthreads();
    for (u32 t = threadIdx.x; t < n; t += 256) chunk[t] = uniq[base + t];
    __syncthreads();
    if (u < (int)U)
      for (u32 j = 0; j < n; ++j) cnt += (chunk[j] < mykey) ? 1u : 0u;
  }
  if (u < (int)U) RANK[u] = cnt;
}

__global__ void k_qrank(const u32* __restrict__ present, const u64* __restrict__ KEYT,
                        const u32* __restrict__ g_htab, const u32* __restrict__ g_pay,
                        const u32* __restrict__ RANK, u32* __restrict__ RANKQ){
  int n = blockIdx.x*blockDim.x + threadIdx.x;
  if (n >= NROWS || present[n] != 1u) return;
  u64 key = KEYT[n];
  u32 h = hash64(key) & DHMASK;
  while (true) {
    u32 cur = g_htab[h];
    if (cur != 0u && KEYT[cur-1u] == key) { RANKQ[n] = RANK[g_pay[h]]; return; }
    h = (h + 1) & DHMASK;
  }
}

__global__ void k_ids(const int* __restrict__ q_data, const u32* __restrict__ RANKQ,
                      float* __restrict__ out_ids){
  int i = blockIdx.x*blockDim.x + threadIdx.x;
  if (i >= NSAMP) return;
  out_ids[i] = (float)RANKQ[clampq(q_data[i])];
}

// one gate's 16-FMA chain from 4 pinned float4s; SAME order/assoc as v7's DOT16
#define DOTG(acc, w0, w1, w2, w3, H) do { \
  acc += (w0).x*(H)[0];  acc += (w0).y*(H)[1];  acc += (w0).z*(H)[2];  acc += (w0).w*(H)[3]; \
  acc += (w1).x*(H)[4];  acc += (w1).y*(H)[5];  acc += (w1).z*(H)[6];  acc += (w1).w*(H)[7]; \
  acc += (w2).x*(H)[8];  acc += (w2).y*(H)[9];  acc += (w2).z*(H)[10]; acc += (w2).w*(H)[11]; \
  acc += (w3).x*(H)[12]; acc += (w3).y*(H)[13]; acc += (w3).z*(H)[14]; acc += (w3).w*(H)[15]; \
} while(0)

// opaque-register pin: value becomes asm-defined -> backend cannot remat it by
// re-executing the load; with the 512-reg budget below it has no reason to spill
#define PINV(v4) asm volatile("" : "+v"((v4).x), "+v"((v4).y), "+v"((v4).z), "+v"((v4).w))

// LSTM v9: v8 + amdgpu_waves_per_eu(1,1). v8 post-mortem: VGPR stayed 68 --
// the pin blocked remat, so the RA SPILLED to scratch instead. Root cause of
// all rounds: the backend schedules for an occupancy TARGET (8 waves/EU ->
// ~64-VGPR budget; 68 observed); __launch_bounds__ only sets the occupancy
// FLOOR. Grid=256 blocks on 256 CUs means 1 block/CU regardless, so that
// target is pure fiction. amdgpu_waves_per_eu(1,1) clamps the target to 1
// wave/EU -> 512-VGPR budget -> keeping the 64 pinned W floats resident is
// free in the RA's own cost model.
__global__ __launch_bounds__(256)
__attribute__((amdgpu_waves_per_eu(1, 1)))
void k_lstm(
    const int* __restrict__ q_data, const float* __restrict__ XW4,
    const float* __restrict__ W_hh,
    const float* __restrict__ W_pred, const float* __restrict__ b_pred,
    const float* __restrict__ init_h, const float* __restrict__ init_c,
    float* __restrict__ out_pred){
  const int b = blockIdx.x;
  const int t = threadIdx.x;
  const int w = t >> 6, l = t & 63;
  const int uo = l & 15, k = l >> 4;            // unit-offset, h-chunk
  const int u = 16*w + uo;                      // unit this lane computes
  __shared__ __align__(64) float Hbuf[SS][64];  // h history; 256B rows
  __shared__ int   sq[SS];
  __shared__ float swp[HH];

  for (int s = t; s < SS; s += 256) sq[s] = clampq(q_data[b*SS + s]);
  if (t < HH) swp[t] = W_pred[t];

  // W_hh rows for unit u, 4 gates, columns [16k,16k+16). Row stride 256B,
  // chunk offset 64B*k -> aligned float4 loads. 16 float4 = 64 VGPRs.
  const float* wb = W_hh + (size_t)u*HH + 16*k;
  float4 wi0 = *(const float4*)(wb +     0), wi1 = *(const float4*)(wb +     4);
  float4 wi2 = *(const float4*)(wb +     8), wi3 = *(const float4*)(wb +    12);
  float4 wf0 = *(const float4*)(wb +  4096), wf1 = *(const float4*)(wb +  4100);
  float4 wf2 = *(const float4*)(wb +  4104), wf3 = *(const float4*)(wb +  4108);
  float4 wg0 = *(const float4*)(wb +  8192), wg1 = *(const float4*)(wb +  8196);
  float4 wg2 = *(const float4*)(wb +  8200), wg3 = *(const float4*)(wb +  8204);
  float4 wo0 = *(const float4*)(wb + 12288), wo1 = *(const float4*)(wb + 12292);
  float4 wo2 = *(const float4*)(wb + 12296), wo3 = *(const float4*)(wb + 12300);
  PINV(wi0); PINV(wi1); PINV(wi2); PINV(wi3);
  PINV(wf0); PINV(wf1); PINV(wf2); PINV(wf3);
  PINV(wg0); PINV(wg1); PINV(wg2); PINV(wg3);
  PINV(wo0); PINV(wo1); PINV(wo2); PINV(wo3);

  // this lane's h-chunk (replicated across the 16 uo-lanes sharing k)
  f16v H = *(const f16v*)(init_h + (size_t)b*HH + 16*k);
  float c  = init_c[b*HH + u];                  // 4 k-copies track c[u] redundantly
  float bp = b_pred[0];
  __syncthreads();

  // depth-2 XW prefetch (4 k-copies load the same float4: L1-hit, harmless)
  float4 xwA = *(const float4*)(XW4 + (size_t)sq[0]*256 + 4*u);
  float4 xwB = *(const float4*)(XW4 + (size_t)sq[1]*256 + 4*u);

  for (int s = 0; s < SS; ++s) {
    int sp = (s + 2 < SS) ? s + 2 : SS - 1;
    float4 xwC = *(const float4*)(XW4 + (size_t)sq[sp]*256 + 4*u);
    float pi=0.f, pf=0.f, pg=0.f, po=0.f;
    DOTG(pi, wi0, wi1, wi2, wi3, H);
    DOTG(pf, wf0, wf1, wf2, wf3, H);
    DOTG(pg, wg0, wg1, wg2, wg3, H);
    DOTG(po, wo0, wo1, wo2, wo3, H);
    // butterfly over k (lanes u,u+16,u+32,u+48 share a unit): (p0+p1)+(p2+p3)
    pi += __shfl_xor(pi, 16, 64); pf += __shfl_xor(pf, 16, 64);
    pg += __shfl_xor(pg, 16, 64); po += __shfl_xor(po, 16, 64);
    pi += __shfl_xor(pi, 32, 64); pf += __shfl_xor(pf, 32, 64);
    pg += __shfl_xor(pg, 32, 64); po += __shfl_xor(po, 32, 64);
    float ai = xwA.x + pi;
    float af = xwA.y + pf;
    float ag = xwA.z + pg;
    float ao = xwA.w + po;
    c = fsigm(af)*c + fsigm(ai)*ftanh(ag);
    float hh = fsigm(ao)*ftanh(c);
    if (l < 16) Hbuf[s][u] = hh;                // k==0 copies write wave's 16 units
    __syncthreads();                            // one cross-wave sync per step
    H = *(const f16v*)(&Hbuf[s][16*k]);         // per-k 64B read: broadcast + 2-way
    xwA = xwB; xwB = xwC;
  }
  __syncthreads();

  // pred epilogue over full Hbuf
  for (int s = t; s < SS; s += 256) {
    float acc = 0.f;
    #pragma unroll 16
    for (int kk = 0; kk < HH; ++kk) {
      int k2 = (kk + t) & 63;                   // swizzle: <=2-way banks (free)
      acc += Hbuf[s][k2] * swp[k2];
    }
    out_pred[b*SS + s] = fsigm(acc + bp);
  }
}

extern "C" void kernel_launch(void* const* d_in, const int* in_sizes, int n_in,
                              void* d_out, int out_size, void* d_ws, size_t ws_size,
                              hipStream_t stream) {
  const int*   q_data  = (const int*)d_in[0];
  const float* emb     = (const float*)d_in[1];
  const float* keym    = (const float*)d_in[2];
  const float* val     = (const float*)d_in[3];
  const float* W_ih    = (const float*)d_in[4];
  const float* W_hh    = (const float*)d_in[5];
  const float* b_ih    = (const float*)d_in[6];
  const float* b_hh    = (const float*)d_in[7];
  const float* W_pred  = (const float*)d_in[8];
  const float* b_pred  = (const float*)d_in[9];
  const float* init_h  = (const float*)d_in[10];
  const float* init_c  = (const float*)d_in[11];

  char* ws = (char*)d_ws;
  float* XW4     = (float*)(ws + 0);          // 10,241,024 (CW overlaid low 32 floats/row)
  float* VW      = (float*)(ws + 10241024);   // 32,768
  u64*  KEYT     = (u64*) (ws + 10273792);    // 80,128
  u64*  uniq     = (u64*) (ws + 10353920);    // 80,128
  u32*  RANK     = (u32*) (ws + 10434048);    // 40,192
  u32*  g_htab   = (u32*) (ws + 10474240);    // 32,768
  u32*  g_pay    = (u32*) (ws + 10507008);    // 32,768
  u32*  counter  = (u32*) (ws + 10539776);    // 64
  u32*  present  = (u32*) (ws + 10539840);    // 40,064
  u32*  RANKQ    = (u32*) (ws + 10579904);    // 40,064
  float* WQT4    = (float*)(ws + 10619968);   // 524,288
  float* KT      = (float*)(ws + 11144256);   // 16,384
  float* WVT     = (float*)(ws + 11160640);   // 262,144
  float* CW      = XW4;                       // overlay: CW[n*256+m]

  float* out_pred = (float*)d_out;
  float* out_ids  = out_pred + NSAMP;

  hipLaunchKernelGGL(k_tr,    dim3(824), dim3(256), 0, stream,
                     W_ih, keym, WQT4, KT, WVT, present);
  hipLaunchKernelGGL(k_front, dim3(NB_ATTN + MM + 200), dim3(256), 0, stream,
                     emb, KT, val, WVT, q_data, CW, KEYT, VW, present);
  hipLaunchKernelGGL(k_dedup, dim3(1), dim3(1024), 0, stream,
                     present, KEYT, g_htab, g_pay, counter, uniq);
  hipLaunchKernelGGL(k_rank,  dim3((NROWS+255)/256), dim3(256), 0, stream, uniq, counter, RANK);
  hipLaunchKernelGGL(k_qrank, dim3((NROWS+255)/256), dim3(256), 0, stream,
                     present, KEYT, g_htab, g_pay, RANK, RANKQ);
  hipLaunchKernelGGL(k_xw,    dim3((NROWS+XR-1)/XR), dim3(256), 0, stream,
                     CW, emb, VW, WQT4, b_ih, b_hh, XW4);
  hipLaunchKernelGGL(k_ids,   dim3((NSAMP+255)/256), dim3(256), 0, stream, q_data, RANKQ, out_ids);
  hipLaunchKernelGGL(k_lstm,  dim3(BB), dim3(256), 0, stream,
                     q_data, XW4, W_hh, W_pred, b_pred, init_h, init_c, out_pred);
}